// Round 4
// baseline (472.811 us; speedup 1.0000x reference)
//
#include <hip/hip_runtime.h>
#include <stdint.h>

// Periodic radius-graph neighbor list (AlphaNet). B=16, N=256, C=27, M=6912.
// Outputs (flat f32 concat): dist [B,N,M], dvec [B,N,M,3], num_neighbors_image [B].
// keep = (1e-4 < dsqr <= 25) AND stable-sort rank < 32
//      == key (f32bits(dsqr)<<32 | m) among the 32 smallest within-radius keys.
//
// R13 = R12 (plain cached stores - proven ~10% over nt in R12) + barrier
// restructure so the zero stream drains UNDER pass-1 compute:
//  - cnt=0 + __syncthreads moved to the very top (no VMEM in flight -> free).
//  - offx/offy/offz LDS table eliminated: each thread loads cell[b] (9
//    broadcast floats, L1) and computes offsets in registers per c with the
//    IDENTICAL expression (n1*cb[0]+n2*cb[3]+n3*cb[6], contract off) ->
//    bit-exact, and the post-phase-A barrier disappears.
//  - Previous structure: stores -> barrier (vmcnt(0) FULL drain) -> pass 1.
//    Now: stores -> pass 1 (regs + LDS atomics only) -> barrier. The drain
//    overlaps ~10-15 us of per-block compute.
// Predicted: ours ~96 -> ~85 us; total ~460 at fill~298 clocks.

constexpr int B_ = 16, N_ = 256, C_ = 27;
constexpr int M_ = N_ * C_;      // 6912
constexpr int MAXC = 256;        // candidate slots; mean ~78, 20-sigma safe
constexpr int KMAX = 32;

typedef float vfloat4 __attribute__((ext_vector_type(4)));

__global__ __launch_bounds__(256)
void nbr_kernel(const float* __restrict__ pos,    // [B,N,3]
                const float* __restrict__ cell,   // [B,3,3]
                float* __restrict__ dist,         // [B,N,M]
                float* __restrict__ dvec,         // [B,N,M,3]
                float* __restrict__ nn)           // [B] (float counts, pre-zeroed)
{
#pragma clang fp contract(off)
    __shared__ unsigned long long keys[MAXC];
    __shared__ float4 vals[MAXC];               // dx,dy,dz,dsq
    __shared__ float4 kept[KMAX];               // dx,dy,dz,dist (by rank)
    __shared__ int    keptm[KMAX];              // candidate index m (by rank)
    __shared__ int cnt;

    const int bi  = blockIdx.x;   // b*N + i
    const int b   = bi >> 8;
    const int i   = bi & 255;
    const int tid = threadIdx.x;

    // ---- barrier while nothing is in flight: publish cnt=0.
    if (tid == 0) cnt = 0;
    __syncthreads();

    // ---- loads first (so their waitcnt doesn't imply store drain).
    const float* pb = pos + b * N_ * 3;
    const float pjx = pb[tid * 3 + 0], pjy = pb[tid * 3 + 1], pjz = pb[tid * 3 + 2];
    const float pix = pb[i * 3 + 0],   piy = pb[i * 3 + 1],   piz = pb[i * 3 + 2];
    const float* cb = cell + b * 9;
    const float c0 = cb[0], c1 = cb[1], c2 = cb[2];
    const float c3 = cb[3], c4 = cb[4], c5 = cb[5];
    const float c6 = cb[6], c7 = cb[7], c8 = cb[8];

    float* drow = dist + (size_t)bi * M_;
    float* vrow = dvec + (size_t)bi * (size_t)(M_ * 3);

    // ---- phase A: zero stream, plain stores (L2 write-combining path).
    // dist row: 1728 float4 = 6*256 + 192 ; dvec row: 5184 float4 = 20*256 + 64.
    {
        vfloat4 z; z.x = 0.f; z.y = 0.f; z.z = 0.f; z.w = 0.f;
        #pragma unroll
        for (int k = 0; k < 6; ++k)
            *(vfloat4*)(drow + 4 * (tid + k * 256)) = z;
        if (tid < 192)
            *(vfloat4*)(drow + 4 * (1536 + tid)) = z;
        #pragma unroll
        for (int k = 0; k < 20; ++k)
            *(vfloat4*)(vrow + 4 * (tid + k * 256)) = z;
        if (tid < 64)
            *(vfloat4*)(vrow + 4 * (5120 + tid)) = z;
    }

    // ---- phase B1 (runs while stores drain; regs + LDS atomics only).
    // Bit-exact numpy order: off = n1*cb[0]+n2*cb[3]+n3*cb[6] etc (contract
    // off, same expression shape as the old LDS table); s = pj + off;
    // d = pi - s; ((dx*dx+dy*dy)+dz*dz).
    #pragma unroll 1
    for (int c = 0; c < C_; ++c) {
        const float n1 = (float)(c / 9 - 1);
        const float n2 = (float)((c / 3) % 3 - 1);
        const float n3 = (float)(c % 3 - 1);
        const float ox = n1 * c0 + n2 * c3 + n3 * c6;
        const float oy = n1 * c1 + n2 * c4 + n3 * c7;
        const float oz = n1 * c2 + n2 * c5 + n3 * c8;
        const float sx = pjx + ox, sy = pjy + oy, sz = pjz + oz;
        const float dx = pix - sx, dy = piy - sy, dz = piz - sz;
        const float dsq = dx * dx + dy * dy + dz * dz;
        if (dsq <= 25.0f && dsq > 1e-4f) {
            const int idx = atomicAdd(&cnt, 1);              // LDS atomic
            if (idx < MAXC) {
                keys[idx] = ((unsigned long long)__float_as_uint(dsq) << 32)
                          | (unsigned)(tid * C_ + c);
                vals[idx] = make_float4(dx, dy, dz, dsq);
            }
        }
    }
    __syncthreads();   // drains stores too - overlapped with all of B1 above

    int K = cnt; if (K > MAXC) K = MAXC;
    const int nk = K < KMAX ? K : KMAX;
    if (tid == 0)
        atomicAdd(&nn[b], (float)nk);

    // ---- phase B2: ranking -> compact kept list (keys unique since m unique;
    // each rank r in [0,nk) written exactly once).
    for (int idx = tid; idx < K; idx += 256) {
        const unsigned long long key = keys[idx];
        int r = 0;
        for (int q = 0; q < K; ++q) r += (keys[q] < key) ? 1 : 0;
        if (r < KMAX) {
            const float4 v = vals[idx];
            kept[r]  = make_float4(v.x, v.y, v.z, sqrtf(v.w));
            keptm[r] = (int)(key & 0xffffffffu);
        }
    }

    // ---- phase C: barrier orders phase-A zero stores before fix-up stores;
    // zero lines still dirty in L2 so the scatter merges there (no HBM RMW).
    __syncthreads();

    if (tid < nk) {
        const float4 v = kept[tid];
        const int m = keptm[tid];
        drow[m]         = v.w;      // dist
        float* vp = vrow + 3 * m;   // dvec
        vp[0] = v.x;
        vp[1] = v.y;
        vp[2] = v.z;
    }
}

extern "C" void kernel_launch(void* const* d_in, const int* in_sizes, int n_in,
                              void* d_out, int out_size, void* d_ws, size_t ws_size,
                              hipStream_t stream)
{
    const float* pos  = (const float*)d_in[0];
    const float* cell = (const float*)d_in[1];
    float* dist = (float*)d_out;
    float* dvec = dist + (size_t)B_ * N_ * M_;
    float* nn   = dvec + (size_t)B_ * N_ * M_ * 3;
    (void)hipMemsetAsync(nn, 0, B_ * sizeof(float), stream);   // zero count tail only
    nbr_kernel<<<dim3(B_ * N_), dim3(256), 0, stream>>>(pos, cell, dist, dvec, nn);
}